// Round 1
// baseline (962.850 us; speedup 1.0000x reference)
//
#include <hip/hip_runtime.h>

#define N_USERS 100000
#define N_ITEMS 50000
#define NEDGE   800000
#define NH      128
#define NTGT    8192
#define NNODE   250000      // 50K item slots (buys) + 100K user (rev) + 100K user (fol)
#define BASE_REV 50000
#define BASE_FOL 150000
#define STILE   4096
#define NTILES  62          // ceil(250000/4096)

// ---------------------------------------------------------------- histogram
__global__ __launch_bounds__(256) void k_hist(
    const int* __restrict__ db, const int* __restrict__ dr,
    const int* __restrict__ df, int* __restrict__ cnt)
{
  int e = blockIdx.x * 256 + threadIdx.x;
  if (e < NEDGE)            atomicAdd(&cnt[db[e]], 1);
  else if (e < 2 * NEDGE)   atomicAdd(&cnt[BASE_REV + dr[e - NEDGE]], 1);
  else if (e < 3 * NEDGE)   atomicAdd(&cnt[BASE_FOL + df[e - 2 * NEDGE]], 1);
}

// ---------------------------------------------------------------- scan (3-phase)
__global__ __launch_bounds__(256) void k_scan_a(const int* __restrict__ cnt,
                                                int* __restrict__ tsum)
{
  int t = threadIdx.x;
  int base = blockIdx.x * STILE + t * 16;
  int s = 0;
  #pragma unroll
  for (int i = 0; i < 16; ++i) { int idx = base + i; s += (idx < NNODE) ? cnt[idx] : 0; }
  __shared__ int red[256];
  red[t] = s; __syncthreads();
  for (int d = 128; d > 0; d >>= 1) { if (t < d) red[t] += red[t + d]; __syncthreads(); }
  if (t == 0) tsum[blockIdx.x] = red[0];
}

__global__ __launch_bounds__(64) void k_scan_b(const int* __restrict__ tsum,
                                               int* __restrict__ tbase)
{
  int t = threadIdx.x;
  int v = (t < NTILES) ? tsum[t] : 0;
  __shared__ int red[64];
  red[t] = v; __syncthreads();
  for (int d = 1; d < 64; d <<= 1) {
    int x = (t >= d) ? red[t - d] : 0;
    __syncthreads();
    red[t] += x;
    __syncthreads();
  }
  tbase[t] = red[t] - v;   // exclusive
}

__global__ __launch_bounds__(256) void k_scan_c(const int* __restrict__ cnt,
                                                const int* __restrict__ tbase,
                                                int* __restrict__ offs)
{
  int t = threadIdx.x;
  int base = blockIdx.x * STILE + t * 16;
  int vals[16]; int s = 0;
  #pragma unroll
  for (int i = 0; i < 16; ++i) {
    int idx = base + i;
    vals[i] = (idx < NNODE) ? cnt[idx] : 0;
    s += vals[i];
  }
  __shared__ int red[256];
  red[t] = s; __syncthreads();
  for (int d = 1; d < 256; d <<= 1) {
    int x = (t >= d) ? red[t - d] : 0;
    __syncthreads();
    red[t] += x;
    __syncthreads();
  }
  int run = tbase[blockIdx.x] + red[t] - s;   // exclusive prefix for this thread
  #pragma unroll
  for (int i = 0; i < 16; ++i) {
    int idx = base + i;
    if (idx < NNODE) offs[idx] = run;
    run += vals[i];
  }
}

// ---------------------------------------------------------------- CSR fill
// After this kernel, offs[n] == end-of-rows for node n (start = end - cnt).
__global__ __launch_bounds__(256) void k_fill(
    const int* __restrict__ sb, const int* __restrict__ db,
    const int* __restrict__ sr, const int* __restrict__ dr,
    const int* __restrict__ sf, const int* __restrict__ df,
    int* __restrict__ offs, int* __restrict__ esrc)
{
  int e = blockIdx.x * 256 + threadIdx.x;
  int idx, s;
  if (e < NEDGE)          { idx = db[e];                    s = sb[e]; }
  else if (e < 2 * NEDGE) { idx = BASE_REV + dr[e - NEDGE]; s = sr[e - NEDGE]; }
  else if (e < 3 * NEDGE) { idx = BASE_FOL + df[e - 2*NEDGE]; s = sf[e - 2*NEDGE]; }
  else return;
  int pos = atomicAdd(&offs[idx], 1);
  esrc[pos] = s;
}

// ---------------------------------------------------------------- combine Wr1+Wr2, bl1+bl2
__global__ __launch_bounds__(256) void k_combine(
    const float* __restrict__ Wr, const float* __restrict__ bl,
    float* __restrict__ Wrc, float* __restrict__ bc)
{
  int i = blockIdx.x * 256 + threadIdx.x;
  if (i < 2 * NH * NH) {
    int l = i >> 14, r = i & (NH * NH - 1);
    Wrc[i] = Wr[(l * 3 + 1) * NH * NH + r] + Wr[(l * 3 + 2) * NH * NH + r];
  } else {
    int j = i - 2 * NH * NH;
    if (j < 2 * NH) {
      int l = j >> 7, r = j & (NH - 1);
      bc[j] = bl[(l * 3 + 1) * NH + r] + bl[(l * 3 + 2) * NH + r];
    }
  }
}

// ---------------------------------------------------------------- layer-1 mean aggregation
// One wave per dst-node slot; lane handles 2 dims via float2.
__global__ __launch_bounds__(256) void k_agg1(
    const int* __restrict__ offs, const int* __restrict__ cnt,
    const int* __restrict__ esrc,
    const float* __restrict__ emb_user, const float* __restrict__ emb_item,
    float* __restrict__ meanL1)
{
  int n = blockIdx.x * 4 + (threadIdx.x >> 6);
  int lane = threadIdx.x & 63;
  if (n >= NNODE) return;
  const float2* table = (n < BASE_REV) ? (const float2*)emb_user
                      : (n < BASE_FOL) ? (const float2*)emb_item
                                       : (const float2*)emb_user;
  int end = offs[n], c = cnt[n], st = end - c;
  float ax = 0.f, ay = 0.f;
  for (int k = st; k < end; ++k) {
    int s = esrc[k];
    float2 v = table[(size_t)s * 64 + lane];
    ax += v.x; ay += v.y;
  }
  float inv = 1.0f / fmaxf((float)c, 1.0f);
  ((float2*)meanL1)[(size_t)n * 64 + lane] = make_float2(ax * inv, ay * inv);
}

// ---------------------------------------------------------------- layer-2 target aggregation
__global__ __launch_bounds__(256) void k_agg_tgt(
    const int* __restrict__ tgt, const int* __restrict__ offs,
    const int* __restrict__ cnt, const int* __restrict__ esrc,
    const float* __restrict__ xu1, const float* __restrict__ xi1,
    float* __restrict__ mrev, float* __restrict__ mfol, float* __restrict__ xsel)
{
  int t = blockIdx.x * 4 + (threadIdx.x >> 6);
  int lane = threadIdx.x & 63;
  if (t >= NTGT) return;
  int u = tgt[t];
  const float2* xip = (const float2*)xi1;
  const float2* xup = (const float2*)xu1;
  {
    int n = BASE_REV + u;
    int end = offs[n], c = cnt[n], st = end - c;
    float ax = 0.f, ay = 0.f;
    for (int k = st; k < end; ++k) {
      int s = esrc[k];
      float2 v = xip[(size_t)s * 64 + lane];
      ax += v.x; ay += v.y;
    }
    float inv = 1.0f / fmaxf((float)c, 1.0f);
    ((float2*)mrev)[(size_t)t * 64 + lane] = make_float2(ax * inv, ay * inv);
  }
  {
    int n = BASE_FOL + u;
    int end = offs[n], c = cnt[n], st = end - c;
    float ax = 0.f, ay = 0.f;
    for (int k = st; k < end; ++k) {
      int s = esrc[k];
      float2 v = xup[(size_t)s * 64 + lane];
      ax += v.x; ay += v.y;
    }
    float inv = 1.0f / fmaxf((float)c, 1.0f);
    ((float2*)mfol)[(size_t)t * 64 + lane] = make_float2(ax * inv, ay * inv);
  }
  ((float2*)xsel)[(size_t)t * 64 + lane] = xup[(size_t)u * 64 + lane];
}

// ---------------------------------------------------------------- fused multi-term GEMM + bias + LN + ReLU
// out[r][c] = relu(LN_row( sum_terms A_t[r][:] . W_t[c][:] + bias[c] ))
// Block: 256 threads, tile = 32 rows x 128 cols (full row -> LN fused).
__global__ __launch_bounds__(256) void k_gemm_ln(
    const float* __restrict__ A0, const float* __restrict__ W0,
    const float* __restrict__ A1, const float* __restrict__ W1,
    const float* __restrict__ A2, const float* __restrict__ W2,
    const float* __restrict__ bias, const float* __restrict__ lng,
    const float* __restrict__ lnb, float* __restrict__ out, int M)
{
  const int t = threadIdx.x;
  const int tx = t & 31, ty = t >> 5;          // tx: col-group, ty: row-group
  const int rowbase = blockIdx.x * 32;
  __shared__ float As[32][36];                  // [kk][row], padded
  __shared__ float Ws[32 * 132];                // [kk][col], padded; reused as C-tile [32][132]

  float acc[4][4];
  #pragma unroll
  for (int i = 0; i < 4; ++i)
    #pragma unroll
    for (int j = 0; j < 4; ++j) acc[i][j] = 0.f;

  #pragma unroll
  for (int term = 0; term < 3; ++term) {
    const float* A = (term == 0) ? A0 : (term == 1) ? A1 : A2;
    const float* W = (term == 0) ? W0 : (term == 1) ? W1 : W2;
    if (A == nullptr) continue;
    for (int kc = 0; kc < NH; kc += 32) {
      // stage A tile k-major: As[kk][row]
      {
        int linear = t * 4;
        int row = linear >> 5, k4 = linear & 31;
        int gr = rowbase + row; if (gr > M - 1) gr = M - 1;
        float4 v = *(const float4*)&A[(size_t)gr * NH + kc + k4];
        As[k4 + 0][row] = v.x; As[k4 + 1][row] = v.y;
        As[k4 + 2][row] = v.z; As[k4 + 3][row] = v.w;
      }
      // stage W tile k-major: Ws[kk*132 + col]
      #pragma unroll
      for (int i = 0; i < 4; ++i) {
        int linear = t * 4 + i * 1024;
        int j = linear >> 5, k4 = linear & 31;
        float4 v = *(const float4*)&W[j * NH + kc + k4];
        Ws[(k4 + 0) * 132 + j] = v.x; Ws[(k4 + 1) * 132 + j] = v.y;
        Ws[(k4 + 2) * 132 + j] = v.z; Ws[(k4 + 3) * 132 + j] = v.w;
      }
      __syncthreads();
      #pragma unroll
      for (int kk = 0; kk < 32; ++kk) {
        float4 a4 = *(const float4*)&As[kk][ty * 4];
        float4 w4 = *(const float4*)&Ws[kk * 132 + tx * 4];
        float ar[4] = {a4.x, a4.y, a4.z, a4.w};
        float wr[4] = {w4.x, w4.y, w4.z, w4.w};
        #pragma unroll
        for (int i = 0; i < 4; ++i)
          #pragma unroll
          for (int j = 0; j < 4; ++j)
            acc[i][j] = fmaf(ar[i], wr[j], acc[i][j]);
      }
      __syncthreads();
    }
  }

  // write acc + bias to C tile in LDS (reuse Ws)
  #pragma unroll
  for (int i = 0; i < 4; ++i) {
    int r = ty * 4 + i;
    #pragma unroll
    for (int j = 0; j < 4; ++j) {
      int c = tx * 4 + j;
      Ws[r * 132 + c] = acc[i][j] + bias[c];
    }
  }
  __syncthreads();

  // LN + ReLU: 8 threads per row, 16 cols each
  {
    int row = t >> 3, sub = t & 7;
    float v[16];
    float s = 0.f, ss = 0.f;
    #pragma unroll
    for (int q = 0; q < 4; ++q) {
      float4 x4 = *(const float4*)&Ws[row * 132 + sub * 16 + q * 4];
      v[q*4+0] = x4.x; v[q*4+1] = x4.y; v[q*4+2] = x4.z; v[q*4+3] = x4.w;
    }
    #pragma unroll
    for (int i = 0; i < 16; ++i) { s += v[i]; ss += v[i] * v[i]; }
    #pragma unroll
    for (int o = 1; o < 8; o <<= 1) { s += __shfl_xor(s, o); ss += __shfl_xor(ss, o); }
    float mu = s * (1.0f / 128.0f);
    float var = ss * (1.0f / 128.0f) - mu * mu;
    float rinv = rsqrtf(var + 1e-5f);
    int gr = rowbase + row;
    if (gr < M) {
      #pragma unroll
      for (int q = 0; q < 4; ++q) {
        int c = sub * 16 + q * 4;
        float4 yo;
        yo.x = fmaxf((v[q*4+0] - mu) * rinv * lng[c+0] + lnb[c+0], 0.f);
        yo.y = fmaxf((v[q*4+1] - mu) * rinv * lng[c+1] + lnb[c+1], 0.f);
        yo.z = fmaxf((v[q*4+2] - mu) * rinv * lng[c+2] + lnb[c+2], 0.f);
        yo.w = fmaxf((v[q*4+3] - mu) * rinv * lng[c+3] + lnb[c+3], 0.f);
        *(float4*)&out[(size_t)gr * NH + c] = yo;
      }
    }
  }
}

// ---------------------------------------------------------------- final MLP: relu(h@W1.T+b1)@W2.T+b2
__global__ __launch_bounds__(256) void k_mlp(
    const float* __restrict__ h2, const float* __restrict__ W1,
    const float* __restrict__ b1, const float* __restrict__ W2,
    const float* __restrict__ b2, float* __restrict__ out)
{
  __shared__ float W1s[64 * 129];
  __shared__ float b1s[64];
  __shared__ float W2s[64];
  __shared__ float sx[4][128];
  int t = threadIdx.x;
  #pragma unroll
  for (int i = 0; i < 32; ++i) {
    int idx = t + 256 * i;             // 0..8191
    int j = idx >> 7, k = idx & 127;
    W1s[j * 129 + k] = W1[idx];
  }
  if (t < 64) { b1s[t] = b1[t]; W2s[t] = W2[t]; }
  __syncthreads();
  int w = t >> 6, lane = t & 63;
  float b2v = b2[0];
  for (int it = 0; it < 8; ++it) {
    int r = blockIdx.x * 32 + it * 4 + w;
    sx[w][lane]      = h2[(size_t)r * NH + lane];
    sx[w][lane + 64] = h2[(size_t)r * NH + lane + 64];
    __syncthreads();
    float h = b1s[lane];
    #pragma unroll
    for (int k = 0; k < 128; ++k) h = fmaf(sx[w][k], W1s[lane * 129 + k], h);
    h = fmaxf(h, 0.f);
    float p = h * W2s[lane];
    #pragma unroll
    for (int o = 32; o > 0; o >>= 1) p += __shfl_down(p, o);
    if (lane == 0) out[r] = p + b2v;
    __syncthreads();
  }
}

// ---------------------------------------------------------------- launch
extern "C" void kernel_launch(void* const* d_in, const int* in_sizes, int n_in,
                              void* d_out, int out_size, void* d_ws, size_t ws_size,
                              hipStream_t stream)
{
  const float* emb_user = (const float*)d_in[0];
  const float* emb_item = (const float*)d_in[1];
  const float* Wl   = (const float*)d_in[2];   // [2,3,128,128]
  const float* bl   = (const float*)d_in[3];   // [2,3,128]
  const float* Wr   = (const float*)d_in[4];   // [2,3,128,128]
  const float* ln_g = (const float*)d_in[5];   // [2,2,128]
  const float* ln_b = (const float*)d_in[6];   // [2,2,128]
  const float* W1   = (const float*)d_in[7];   // [64,128]
  const float* b1   = (const float*)d_in[8];   // [64]
  const float* W2   = (const float*)d_in[9];   // [1,64]
  const float* b2   = (const float*)d_in[10];  // [1]
  const int* src_buys = (const int*)d_in[11];
  const int* dst_buys = (const int*)d_in[12];
  const int* src_rev  = (const int*)d_in[13];
  const int* dst_rev  = (const int*)d_in[14];
  const int* src_fol  = (const int*)d_in[15];
  const int* dst_fol  = (const int*)d_in[16];
  const int* tgt      = (const int*)d_in[17];
  float* outp = (float*)d_out;

  char* wp = (char*)d_ws;
  size_t ob = 0;
  auto take = [&](size_t bytes) -> void* {
    void* p = wp + ob;
    ob += (bytes + 255) & ~(size_t)255;
    return p;
  };
  int*   cnt    = (int*)  take((size_t)NNODE * 4);
  int*   offs   = (int*)  take((size_t)NNODE * 4);
  int*   tsum   = (int*)  take(64 * 4);
  int*   tbase  = (int*)  take(64 * 4);
  int*   esrc   = (int*)  take((size_t)3 * NEDGE * 4);
  float* Wrc    = (float*)take((size_t)2 * NH * NH * 4);
  float* bc     = (float*)take((size_t)2 * NH * 4);
  float* meanL1 = (float*)take((size_t)NNODE * NH * 4);
  float* xu1    = (float*)take((size_t)N_USERS * NH * 4);
  float* xi1    = (float*)take((size_t)N_ITEMS * NH * 4);
  float* mrev2  = (float*)take((size_t)NTGT * NH * 4);
  float* mfol2  = (float*)take((size_t)NTGT * NH * 4);
  float* xsel2  = (float*)take((size_t)NTGT * NH * 4);
  float* h2     = (float*)take((size_t)NTGT * NH * 4);

  hipMemsetAsync(cnt, 0, (size_t)NNODE * 4, stream);

  k_combine<<<(2 * NH * NH + 2 * NH + 255) / 256, 256, 0, stream>>>(Wr, bl, Wrc, bc);
  k_hist<<<(3 * NEDGE + 255) / 256, 256, 0, stream>>>(dst_buys, dst_rev, dst_fol, cnt);
  k_scan_a<<<NTILES, 256, 0, stream>>>(cnt, tsum);
  k_scan_b<<<1, 64, 0, stream>>>(tsum, tbase);
  k_scan_c<<<NTILES, 256, 0, stream>>>(cnt, tbase, offs);
  k_fill<<<(3 * NEDGE + 255) / 256, 256, 0, stream>>>(
      src_buys, dst_buys, src_rev, dst_rev, src_fol, dst_fol, offs, esrc);
  k_agg1<<<NNODE / 4, 256, 0, stream>>>(offs, cnt, esrc, emb_user, emb_item, meanL1);

  // layer-1 item: relu(LN(mean_buys@Wl00.T + xi0@Wr00.T + bl00))
  k_gemm_ln<<<(N_ITEMS + 31) / 32, 256, 0, stream>>>(
      meanL1, Wl + 0 * NH * NH,
      emb_item, Wr + 0 * NH * NH,
      nullptr, nullptr,
      bl + 0 * NH, ln_g + 1 * NH, ln_b + 1 * NH, xi1, N_ITEMS);

  // layer-1 user: relu(LN(mean_rev@Wl01.T + mean_fol@Wl02.T + xu0@(Wr01+Wr02).T + bl01+bl02))
  k_gemm_ln<<<N_USERS / 32, 256, 0, stream>>>(
      meanL1 + (size_t)BASE_REV * NH, Wl + 1 * NH * NH,
      meanL1 + (size_t)BASE_FOL * NH, Wl + 2 * NH * NH,
      emb_user, Wrc,
      bc, ln_g + 0 * NH, ln_b + 0 * NH, xu1, N_USERS);

  // layer-2 aggregation at targets only (item update is dead code)
  k_agg_tgt<<<NTGT / 4, 256, 0, stream>>>(tgt, offs, cnt, esrc, xu1, xi1, mrev2, mfol2, xsel2);

  // layer-2 user at targets
  k_gemm_ln<<<NTGT / 32, 256, 0, stream>>>(
      mrev2, Wl + (1 * 3 + 1) * NH * NH,
      mfol2, Wl + (1 * 3 + 2) * NH * NH,
      xsel2, Wrc + NH * NH,
      bc + NH, ln_g + 2 * NH, ln_b + 2 * NH, h2, NTGT);

  // final MLP
  k_mlp<<<NTGT / 32, 256, 0, stream>>>(h2, W1, b1, W2, b2, outp);
}

// Round 2
// 863.470 us; speedup vs baseline: 1.1151x; 1.1151x over previous
//
#include <hip/hip_runtime.h>

#define N_USERS 100000
#define N_ITEMS 50000
#define NEDGE   800000
#define NH      128
#define NTGT    8192
#define NNODE   250000      // 50K item slots (buys) + 100K user (rev) + 100K user (fol)
#define BASE_REV 50000
#define BASE_FOL 150000
#define STILE   4096
#define NTILES  62          // ceil(250000/4096)

// ---------------------------------------------------------------- histogram
__global__ __launch_bounds__(256) void k_hist(
    const int* __restrict__ db, const int* __restrict__ dr,
    const int* __restrict__ df, int* __restrict__ cnt)
{
  int e = blockIdx.x * 256 + threadIdx.x;
  if (e < NEDGE)            atomicAdd(&cnt[db[e]], 1);
  else if (e < 2 * NEDGE)   atomicAdd(&cnt[BASE_REV + dr[e - NEDGE]], 1);
  else if (e < 3 * NEDGE)   atomicAdd(&cnt[BASE_FOL + df[e - 2 * NEDGE]], 1);
}

// ---------------------------------------------------------------- scan (3-phase)
__global__ __launch_bounds__(256) void k_scan_a(const int* __restrict__ cnt,
                                                int* __restrict__ tsum)
{
  int t = threadIdx.x;
  int base = blockIdx.x * STILE + t * 16;
  int s = 0;
  #pragma unroll
  for (int i = 0; i < 16; ++i) { int idx = base + i; s += (idx < NNODE) ? cnt[idx] : 0; }
  __shared__ int red[256];
  red[t] = s; __syncthreads();
  for (int d = 128; d > 0; d >>= 1) { if (t < d) red[t] += red[t + d]; __syncthreads(); }
  if (t == 0) tsum[blockIdx.x] = red[0];
}

__global__ __launch_bounds__(64) void k_scan_b(const int* __restrict__ tsum,
                                               int* __restrict__ tbase)
{
  int t = threadIdx.x;
  int v = (t < NTILES) ? tsum[t] : 0;
  __shared__ int red[64];
  red[t] = v; __syncthreads();
  for (int d = 1; d < 64; d <<= 1) {
    int x = (t >= d) ? red[t - d] : 0;
    __syncthreads();
    red[t] += x;
    __syncthreads();
  }
  tbase[t] = red[t] - v;   // exclusive
}

__global__ __launch_bounds__(256) void k_scan_c(const int* __restrict__ cnt,
                                                const int* __restrict__ tbase,
                                                int* __restrict__ offs)
{
  int t = threadIdx.x;
  int base = blockIdx.x * STILE + t * 16;
  int vals[16]; int s = 0;
  #pragma unroll
  for (int i = 0; i < 16; ++i) {
    int idx = base + i;
    vals[i] = (idx < NNODE) ? cnt[idx] : 0;
    s += vals[i];
  }
  __shared__ int red[256];
  red[t] = s; __syncthreads();
  for (int d = 1; d < 256; d <<= 1) {
    int x = (t >= d) ? red[t - d] : 0;
    __syncthreads();
    red[t] += x;
    __syncthreads();
  }
  int run = tbase[blockIdx.x] + red[t] - s;   // exclusive prefix for this thread
  #pragma unroll
  for (int i = 0; i < 16; ++i) {
    int idx = base + i;
    if (idx < NNODE) offs[idx] = run;
    run += vals[i];
  }
}

// ---------------------------------------------------------------- CSR fill
// After this kernel, offs[n] == end-of-rows for node n (start = end - cnt).
__global__ __launch_bounds__(256) void k_fill(
    const int* __restrict__ sb, const int* __restrict__ db,
    const int* __restrict__ sr, const int* __restrict__ dr,
    const int* __restrict__ sf, const int* __restrict__ df,
    int* __restrict__ offs, int* __restrict__ esrc)
{
  int e = blockIdx.x * 256 + threadIdx.x;
  int idx, s;
  if (e < NEDGE)          { idx = db[e];                    s = sb[e]; }
  else if (e < 2 * NEDGE) { idx = BASE_REV + dr[e - NEDGE]; s = sr[e - NEDGE]; }
  else if (e < 3 * NEDGE) { idx = BASE_FOL + df[e - 2*NEDGE]; s = sf[e - 2*NEDGE]; }
  else return;
  int pos = atomicAdd(&offs[idx], 1);
  esrc[pos] = s;
}

// ---------------------------------------------------------------- combine Wr1+Wr2, bl1+bl2
__global__ __launch_bounds__(256) void k_combine(
    const float* __restrict__ Wr, const float* __restrict__ bl,
    float* __restrict__ Wrc, float* __restrict__ bc)
{
  int i = blockIdx.x * 256 + threadIdx.x;
  if (i < 2 * NH * NH) {
    int l = i >> 14, r = i & (NH * NH - 1);
    Wrc[i] = Wr[(l * 3 + 1) * NH * NH + r] + Wr[(l * 3 + 2) * NH * NH + r];
  } else {
    int j = i - 2 * NH * NH;
    if (j < 2 * NH) {
      int l = j >> 7, r = j & (NH - 1);
      bc[j] = bl[(l * 3 + 1) * NH + r] + bl[(l * 3 + 2) * NH + r];
    }
  }
}

// ---------------------------------------------------------------- layer-1 mean aggregation
// Half-wave (32 lanes * float4 = full 512B row) per node; 4-deep unrolled
// edge loop -> 4 outstanding row-gathers per half-wave (MLP for latency).
__global__ __launch_bounds__(256) void k_agg1(
    const int* __restrict__ offs, const int* __restrict__ cnt,
    const int* __restrict__ esrc,
    const float* __restrict__ emb_user, const float* __restrict__ emb_item,
    float* __restrict__ meanL1)
{
  int n = blockIdx.x * 8 + (threadIdx.x >> 5);
  int sl = threadIdx.x & 31;
  if (n >= NNODE) return;
  const float4* table = (n < BASE_REV) ? (const float4*)emb_user
                      : (n < BASE_FOL) ? (const float4*)emb_item
                                       : (const float4*)emb_user;
  int end = offs[n], c = cnt[n], st = end - c;
  float ax = 0.f, ay = 0.f, az = 0.f, aw = 0.f;
  int k = st;
  for (; k + 3 < end; k += 4) {
    int s0 = esrc[k], s1 = esrc[k + 1], s2 = esrc[k + 2], s3 = esrc[k + 3];
    float4 v0 = table[(size_t)s0 * 32 + sl];
    float4 v1 = table[(size_t)s1 * 32 + sl];
    float4 v2 = table[(size_t)s2 * 32 + sl];
    float4 v3 = table[(size_t)s3 * 32 + sl];
    ax += (v0.x + v1.x) + (v2.x + v3.x);
    ay += (v0.y + v1.y) + (v2.y + v3.y);
    az += (v0.z + v1.z) + (v2.z + v3.z);
    aw += (v0.w + v1.w) + (v2.w + v3.w);
  }
  for (; k < end; ++k) {
    float4 v = table[(size_t)esrc[k] * 32 + sl];
    ax += v.x; ay += v.y; az += v.z; aw += v.w;
  }
  float inv = 1.0f / fmaxf((float)c, 1.0f);
  float4 o; o.x = ax * inv; o.y = ay * inv; o.z = az * inv; o.w = aw * inv;
  ((float4*)meanL1)[(size_t)n * 32 + sl] = o;
}

// ---------------------------------------------------------------- layer-2 target aggregation
// Half-wave per (target, conv). which==0: rev_buys (items), also copies xsel.
__global__ __launch_bounds__(256) void k_agg_tgt(
    const int* __restrict__ tgt, const int* __restrict__ offs,
    const int* __restrict__ cnt, const int* __restrict__ esrc,
    const float* __restrict__ xu1, const float* __restrict__ xi1,
    float* __restrict__ mrev, float* __restrict__ mfol, float* __restrict__ xsel)
{
  int hw = blockIdx.x * 8 + (threadIdx.x >> 5);
  int sl = threadIdx.x & 31;
  int t = hw >> 1, which = hw & 1;
  if (t >= NTGT) return;
  int u = tgt[t];
  int n = (which ? BASE_FOL : BASE_REV) + u;
  const float4* table = which ? (const float4*)xu1 : (const float4*)xi1;
  int end = offs[n], c = cnt[n], st = end - c;
  float ax = 0.f, ay = 0.f, az = 0.f, aw = 0.f;
  int k = st;
  for (; k + 3 < end; k += 4) {
    int s0 = esrc[k], s1 = esrc[k + 1], s2 = esrc[k + 2], s3 = esrc[k + 3];
    float4 v0 = table[(size_t)s0 * 32 + sl];
    float4 v1 = table[(size_t)s1 * 32 + sl];
    float4 v2 = table[(size_t)s2 * 32 + sl];
    float4 v3 = table[(size_t)s3 * 32 + sl];
    ax += (v0.x + v1.x) + (v2.x + v3.x);
    ay += (v0.y + v1.y) + (v2.y + v3.y);
    az += (v0.z + v1.z) + (v2.z + v3.z);
    aw += (v0.w + v1.w) + (v2.w + v3.w);
  }
  for (; k < end; ++k) {
    float4 v = table[(size_t)esrc[k] * 32 + sl];
    ax += v.x; ay += v.y; az += v.z; aw += v.w;
  }
  float inv = 1.0f / fmaxf((float)c, 1.0f);
  float4 o; o.x = ax * inv; o.y = ay * inv; o.z = az * inv; o.w = aw * inv;
  if (which) {
    ((float4*)mfol)[(size_t)t * 32 + sl] = o;
  } else {
    ((float4*)mrev)[(size_t)t * 32 + sl] = o;
    ((float4*)xsel)[(size_t)t * 32 + sl] = ((const float4*)xu1)[(size_t)u * 32 + sl];
  }
}

// ---------------------------------------------------------------- fused multi-term GEMM + bias + LN + ReLU
// out[r][c] = relu(LN_row( sum_terms A_t[r][:] . W_t[c][:] + bias[c] ))
// Block: 256 threads, tile 64 rows x 128 cols; 8x4 acc per thread.
// Row r's 128 cols live entirely in half-wave (ty = t>>5) -> LN via shfl_xor,
// no LDS C-tile round-trip.
__global__ __launch_bounds__(256) void k_gemm_ln(
    const float* __restrict__ A0, const float* __restrict__ W0,
    const float* __restrict__ A1, const float* __restrict__ W1,
    const float* __restrict__ A2, const float* __restrict__ W2,
    const float* __restrict__ bias, const float* __restrict__ lng,
    const float* __restrict__ lnb, float* __restrict__ out, int M)
{
  const int t = threadIdx.x;
  const int tx = t & 31, ty = t >> 5;          // tx: col-group (4 cols), ty: row-group (8 rows)
  const int rowbase = blockIdx.x * 64;
  __shared__ float As[32][68];                  // [kk][row], stride 68 (16B-aligned, broadcast reads)
  __shared__ float Ws[32 * 132];                // [kk][col], padded

  float acc[8][4];
  #pragma unroll
  for (int i = 0; i < 8; ++i)
    #pragma unroll
    for (int j = 0; j < 4; ++j) acc[i][j] = 0.f;

  const int arow = t >> 2;                // 0..63
  const int ak8  = (t & 3) * 8;           // 0,8,16,24

  #pragma unroll
  for (int term = 0; term < 3; ++term) {
    const float* A = (term == 0) ? A0 : (term == 1) ? A1 : A2;
    const float* W = (term == 0) ? W0 : (term == 1) ? W1 : W2;
    if (A == nullptr) continue;
    for (int kc = 0; kc < NH; kc += 32) {
      // stage A tile k-major: As[kk][row] — each thread 8 floats of one row
      {
        int gr = rowbase + arow; if (gr > M - 1) gr = M - 1;
        const float* ap = &A[(size_t)gr * NH + kc + ak8];
        float4 v0 = *(const float4*)(ap);
        float4 v1 = *(const float4*)(ap + 4);
        As[ak8 + 0][arow] = v0.x; As[ak8 + 1][arow] = v0.y;
        As[ak8 + 2][arow] = v0.z; As[ak8 + 3][arow] = v0.w;
        As[ak8 + 4][arow] = v1.x; As[ak8 + 5][arow] = v1.y;
        As[ak8 + 6][arow] = v1.z; As[ak8 + 7][arow] = v1.w;
      }
      // stage W tile k-major: Ws[kk*132 + col]
      #pragma unroll
      for (int i = 0; i < 4; ++i) {
        int linear = t * 4 + i * 1024;
        int j = linear >> 5, k4 = linear & 31;
        float4 v = *(const float4*)&W[j * NH + kc + k4];
        Ws[(k4 + 0) * 132 + j] = v.x; Ws[(k4 + 1) * 132 + j] = v.y;
        Ws[(k4 + 2) * 132 + j] = v.z; Ws[(k4 + 3) * 132 + j] = v.w;
      }
      __syncthreads();
      #pragma unroll
      for (int kk = 0; kk < 32; ++kk) {
        float4 alo = *(const float4*)&As[kk][ty * 8];
        float4 ahi = *(const float4*)&As[kk][ty * 8 + 4];
        float4 w4  = *(const float4*)&Ws[kk * 132 + tx * 4];
        float ar[8] = {alo.x, alo.y, alo.z, alo.w, ahi.x, ahi.y, ahi.z, ahi.w};
        float wr[4] = {w4.x, w4.y, w4.z, w4.w};
        #pragma unroll
        for (int i = 0; i < 8; ++i)
          #pragma unroll
          for (int j = 0; j < 4; ++j)
            acc[i][j] = fmaf(ar[i], wr[j], acc[i][j]);
      }
      __syncthreads();
    }
  }

  // epilogue: bias + per-row LN (half-wave shuffle) + ReLU + store
  float4 b4 = *(const float4*)&bias[tx * 4];
  float4 g4 = *(const float4*)&lng[tx * 4];
  float4 l4 = *(const float4*)&lnb[tx * 4];
  float bb[4] = {b4.x, b4.y, b4.z, b4.w};
  float gg[4] = {g4.x, g4.y, g4.z, g4.w};
  float ll[4] = {l4.x, l4.y, l4.z, l4.w};

  #pragma unroll
  for (int i = 0; i < 8; ++i) {
    float s = 0.f, ss = 0.f;
    #pragma unroll
    for (int j = 0; j < 4; ++j) {
      float v = acc[i][j] + bb[j];
      acc[i][j] = v;
      s += v; ss += v * v;
    }
    #pragma unroll
    for (int o = 1; o < 32; o <<= 1) { s += __shfl_xor(s, o); ss += __shfl_xor(ss, o); }
    float mu = s * (1.0f / 128.0f);
    float var = ss * (1.0f / 128.0f) - mu * mu;
    float rinv = rsqrtf(var + 1e-5f);
    int gr = rowbase + ty * 8 + i;
    if (gr < M) {
      float4 y;
      y.x = fmaxf((acc[i][0] - mu) * rinv * gg[0] + ll[0], 0.f);
      y.y = fmaxf((acc[i][1] - mu) * rinv * gg[1] + ll[1], 0.f);
      y.z = fmaxf((acc[i][2] - mu) * rinv * gg[2] + ll[2], 0.f);
      y.w = fmaxf((acc[i][3] - mu) * rinv * gg[3] + ll[3], 0.f);
      *(float4*)&out[(size_t)gr * NH + tx * 4] = y;
    }
  }
}

// ---------------------------------------------------------------- final MLP: relu(h@W1.T+b1)@W2.T+b2
__global__ __launch_bounds__(256) void k_mlp(
    const float* __restrict__ h2, const float* __restrict__ W1,
    const float* __restrict__ b1, const float* __restrict__ W2,
    const float* __restrict__ b2, float* __restrict__ out)
{
  __shared__ float W1s[64 * 129];
  __shared__ float b1s[64];
  __shared__ float W2s[64];
  __shared__ float sx[4][128];
  int t = threadIdx.x;
  #pragma unroll
  for (int i = 0; i < 32; ++i) {
    int idx = t + 256 * i;             // 0..8191
    int j = idx >> 7, k = idx & 127;
    W1s[j * 129 + k] = W1[idx];
  }
  if (t < 64) { b1s[t] = b1[t]; W2s[t] = W2[t]; }
  __syncthreads();
  int w = t >> 6, lane = t & 63;
  float b2v = b2[0];
  for (int it = 0; it < 8; ++it) {
    int r = blockIdx.x * 32 + it * 4 + w;
    sx[w][lane]      = h2[(size_t)r * NH + lane];
    sx[w][lane + 64] = h2[(size_t)r * NH + lane + 64];
    __syncthreads();
    float h = b1s[lane];
    #pragma unroll
    for (int k = 0; k < 128; ++k) h = fmaf(sx[w][k], W1s[lane * 129 + k], h);
    h = fmaxf(h, 0.f);
    float p = h * W2s[lane];
    #pragma unroll
    for (int o = 32; o > 0; o >>= 1) p += __shfl_down(p, o);
    if (lane == 0) out[r] = p + b2v;
    __syncthreads();
  }
}

// ---------------------------------------------------------------- launch
extern "C" void kernel_launch(void* const* d_in, const int* in_sizes, int n_in,
                              void* d_out, int out_size, void* d_ws, size_t ws_size,
                              hipStream_t stream)
{
  const float* emb_user = (const float*)d_in[0];
  const float* emb_item = (const float*)d_in[1];
  const float* Wl   = (const float*)d_in[2];   // [2,3,128,128]
  const float* bl   = (const float*)d_in[3];   // [2,3,128]
  const float* Wr   = (const float*)d_in[4];   // [2,3,128,128]
  const float* ln_g = (const float*)d_in[5];   // [2,2,128]
  const float* ln_b = (const float*)d_in[6];   // [2,2,128]
  const float* W1   = (const float*)d_in[7];   // [64,128]
  const float* b1   = (const float*)d_in[8];   // [64]
  const float* W2   = (const float*)d_in[9];   // [1,64]
  const float* b2   = (const float*)d_in[10];  // [1]
  const int* src_buys = (const int*)d_in[11];
  const int* dst_buys = (const int*)d_in[12];
  const int* src_rev  = (const int*)d_in[13];
  const int* dst_rev  = (const int*)d_in[14];
  const int* src_fol  = (const int*)d_in[15];
  const int* dst_fol  = (const int*)d_in[16];
  const int* tgt      = (const int*)d_in[17];
  float* outp = (float*)d_out;

  char* wp = (char*)d_ws;
  size_t ob = 0;
  auto take = [&](size_t bytes) -> void* {
    void* p = wp + ob;
    ob += (bytes + 255) & ~(size_t)255;
    return p;
  };
  int*   cnt    = (int*)  take((size_t)NNODE * 4);
  int*   offs   = (int*)  take((size_t)NNODE * 4);
  int*   tsum   = (int*)  take(64 * 4);
  int*   tbase  = (int*)  take(64 * 4);
  int*   esrc   = (int*)  take((size_t)3 * NEDGE * 4);
  float* Wrc    = (float*)take((size_t)2 * NH * NH * 4);
  float* bc     = (float*)take((size_t)2 * NH * 4);
  float* meanL1 = (float*)take((size_t)NNODE * NH * 4);
  float* xu1    = (float*)take((size_t)N_USERS * NH * 4);
  float* xi1    = (float*)take((size_t)N_ITEMS * NH * 4);
  float* mrev2  = (float*)take((size_t)NTGT * NH * 4);
  float* mfol2  = (float*)take((size_t)NTGT * NH * 4);
  float* xsel2  = (float*)take((size_t)NTGT * NH * 4);
  float* h2     = (float*)take((size_t)NTGT * NH * 4);

  hipMemsetAsync(cnt, 0, (size_t)NNODE * 4, stream);

  k_combine<<<(2 * NH * NH + 2 * NH + 255) / 256, 256, 0, stream>>>(Wr, bl, Wrc, bc);
  k_hist<<<(3 * NEDGE + 255) / 256, 256, 0, stream>>>(dst_buys, dst_rev, dst_fol, cnt);
  k_scan_a<<<NTILES, 256, 0, stream>>>(cnt, tsum);
  k_scan_b<<<1, 64, 0, stream>>>(tsum, tbase);
  k_scan_c<<<NTILES, 256, 0, stream>>>(cnt, tbase, offs);
  k_fill<<<(3 * NEDGE + 255) / 256, 256, 0, stream>>>(
      src_buys, dst_buys, src_rev, dst_rev, src_fol, dst_fol, offs, esrc);
  k_agg1<<<(NNODE + 7) / 8, 256, 0, stream>>>(offs, cnt, esrc, emb_user, emb_item, meanL1);

  // layer-1 item: relu(LN(mean_buys@Wl00.T + xi0@Wr00.T + bl00))
  k_gemm_ln<<<(N_ITEMS + 63) / 64, 256, 0, stream>>>(
      meanL1, Wl + 0 * NH * NH,
      emb_item, Wr + 0 * NH * NH,
      nullptr, nullptr,
      bl + 0 * NH, ln_g + 1 * NH, ln_b + 1 * NH, xi1, N_ITEMS);

  // layer-1 user: relu(LN(mean_rev@Wl01.T + mean_fol@Wl02.T + xu0@(Wr01+Wr02).T + bl01+bl02))
  k_gemm_ln<<<(N_USERS + 63) / 64, 256, 0, stream>>>(
      meanL1 + (size_t)BASE_REV * NH, Wl + 1 * NH * NH,
      meanL1 + (size_t)BASE_FOL * NH, Wl + 2 * NH * NH,
      emb_user, Wrc,
      bc, ln_g + 0 * NH, ln_b + 0 * NH, xu1, N_USERS);

  // layer-2 aggregation at targets only (item update is dead code)
  k_agg_tgt<<<(2 * NTGT + 7) / 8, 256, 0, stream>>>(tgt, offs, cnt, esrc, xu1, xi1, mrev2, mfol2, xsel2);

  // layer-2 user at targets
  k_gemm_ln<<<(NTGT + 63) / 64, 256, 0, stream>>>(
      mrev2, Wl + (1 * 3 + 1) * NH * NH,
      mfol2, Wl + (1 * 3 + 2) * NH * NH,
      xsel2, Wrc + NH * NH,
      bc + NH, ln_g + 2 * NH, ln_b + 2 * NH, h2, NTGT);

  // final MLP
  k_mlp<<<NTGT / 32, 256, 0, stream>>>(h2, W1, b1, W2, b2, outp);
}